// Round 10
// baseline (255.006 us; speedup 1.0000x reference)
//
#include <hip/hip_runtime.h>

// Problem constants (match reference)
#define BATCH 8192
#define TSTEPS 200
#define FEAT 16
#define HID 32
#define GATES 128   // 4*HID, Keras order: i | f | cc | o
#define DOUT 60
#define ROWS 16     // batch rows per block (one MFMA N-tile)
#define HSTRIDE 40  // LDS h row stride in halves (80 B)

typedef __fp16 half2v __attribute__((ext_vector_type(2)));
typedef __fp16 half4v __attribute__((ext_vector_type(4)));
typedef __fp16 half8v __attribute__((ext_vector_type(8)));
typedef float  float2v __attribute__((ext_vector_type(2)));
typedef float  float4v __attribute__((ext_vector_type(4)));

__device__ __forceinline__ half2v pkrtz(float a, float b) {
    return __builtin_amdgcn_cvt_pkrtz(a, b);
}

__device__ __forceinline__ half4v pack4(float4 v) {
    half2v lo = pkrtz(v.x, v.y);
    half2v hi = pkrtz(v.z, v.w);
    half4v r;
    r[0] = lo[0]; r[1] = lo[1]; r[2] = hi[0]; r[3] = hi[1];
    return r;
}

// Two-wave gate-split (R10): wave w owns h-units [16w, 16w+16), i.e. gate
// columns 32*tt + 16*w + m for gate-type tt (0:i 1:f 2:cc 3:o), m = 0..15.
// Per wave: 4 hU MFMA (16x16x32) + 4 xW MFMA (16x16x16); epilogue = 4
// outputs/lane (12 exp2 + 2 rcp) -- HALF of R9's per-wave issue. Lane
// (g,n16) holds D rows m=4g+r -> emits h[units 16w+4g..16w+4g+3][row n16]
// as ONE contiguous 8B ds_write. Next step's B-frag (units 8g..8g+7, row
// n16) is ONE ds_read_b128. One __syncthreads per step; x prefetched >=2
// full steps ahead so the barrier's vmcnt drain is free (R0's mistake).
// 512 blocks x 2 waves = 1024 waves = 1 wave on ALL 1024 SIMDs.
// Fragment layouts (gfx950, verified R2/R4/R9):
//   16x16x32 A[m][k]: m=lane&15, k=(lane>>4)*8+j ; B[k][n]: n=lane&15, same k
//   16x16x16 A[m][k]: m=lane&15, k=(lane>>4)*4+j ; B[k][n]: n=lane&15, same k
//   D[m][n]: n=lane&15, m=(lane>>4)*4+r
// Epilogue math = R9's packed-f32 form (bit-identical numerics):
//   gates prescaled by -log2(e); num = c*d_i + relu(cc)*d_f; ee = d_i*d_f*d_o
//   c' = num*(ie*d_o); h = relu(num)*ie; ie via one rcp per element-pair.
template <bool DO_XW, bool DO_LOAD, int LOFF>
__device__ __forceinline__ void lstm_step(
    float4& XN, const float* xp,
    const half8v (&aU)[4], const half4v (&aW)[4], const float4v (&bias)[4],
    float4v (&accx)[4], float2v (&cst)[2],
    const __fp16* hr, __fp16* hw, int hroff, int hwoff)
{
    half8v hB = *reinterpret_cast<const half8v*>(&hr[hroff]);

    float4v acc[4];
    #pragma unroll
    for (int tt = 0; tt < 4; tt++)
        acc[tt] = __builtin_amdgcn_mfma_f32_16x16x32_f16(
            aU[tt], hB, accx[tt], 0, 0, 0);

    if (DO_XW) {
        half4v ax = pack4(XN);
        #pragma unroll
        for (int tt = 0; tt < 4; tt++)
            accx[tt] = __builtin_amdgcn_mfma_f32_16x16x16f16(
                aW[tt], ax, bias[tt], 0, 0, 0);
    }
    if (DO_LOAD)
        XN = *reinterpret_cast<const float4*>(xp + LOFF);

    const float2v one  = {1.0f, 1.0f};
    const float2v zero = {0.0f, 0.0f};
    union { half4v v; half2v h2[2]; } hv;
    #pragma unroll
    for (int p = 0; p < 2; p++) {
        float2v ei, ef, eo;
        ei[0] = __builtin_amdgcn_exp2f(acc[0][2 * p]);
        ei[1] = __builtin_amdgcn_exp2f(acc[0][2 * p + 1]);
        ef[0] = __builtin_amdgcn_exp2f(acc[1][2 * p]);
        ef[1] = __builtin_amdgcn_exp2f(acc[1][2 * p + 1]);
        eo[0] = __builtin_amdgcn_exp2f(acc[3][2 * p]);
        eo[1] = __builtin_amdgcn_exp2f(acc[3][2 * p + 1]);
        float2v di  = one + ei;
        float2v df  = one + ef;
        float2v dov = one + eo;
        float2v cc2 = {acc[2][2 * p], acc[2][2 * p + 1]};
        float2v rc  = __builtin_elementwise_max(cc2, zero);
        float2v num = __builtin_elementwise_fma(cst[p], di, rc * df);
        float2v ee  = (di * df) * dov;
        float   Q   = __builtin_amdgcn_rcpf(ee[0] * ee[1]);
        float2v ie  = {Q * ee[1], Q * ee[0]};
        float2v c2  = num * (ie * dov);
        cst[p] = c2;
        float2v h2  = __builtin_elementwise_max(num, zero) * ie;
        hv.h2[p] = pkrtz(h2[0], h2[1]);
    }
    *reinterpret_cast<half4v*>(&hw[hwoff]) = hv.v;   // units 16w+4g..+3, row n16
    __syncthreads();   // h_{t+1} complete; vmcnt already 0 (deep prefetch)
}

__global__ __launch_bounds__(128, 1) void lstm_mfma(
    const float* __restrict__ x,    // [B, T, F]
    const float* __restrict__ W,    // [F, 128]
    const float* __restrict__ U,    // [H, 128]
    const float* __restrict__ bg,   // [128]
    const float* __restrict__ W1,   // [H, 60]
    const float* __restrict__ b1,   // [60]
    const float* __restrict__ W2,   // [H, 60]
    const float* __restrict__ b2,   // [60]
    float* __restrict__ out)        // [2 * B * 60] (long || lat)
{
    const int tid  = threadIdx.x;   // 128 threads = 2 waves
    const int lane = tid & 63;
    const int w    = tid >> 6;      // unit-half: 0 or 1
    const int n16  = lane & 15;     // batch row within tile
    const int g    = lane >> 4;     // k-quad / D-row-quad
    const int b0   = blockIdx.x * ROWS;

    __shared__ __align__(16) __fp16 hbuf[2][ROWS * HSTRIDE];

    // ---- stationary A-frags: U^T (K=32), W^T (K=16), bias (per D-row) ----
    half8v  aU[4];
    half4v  aW[4];
    float4v bias[4];
    #pragma unroll
    for (int tt = 0; tt < 4; tt++) {
        const float s = (tt == 2) ? 1.0f : -1.44269504088896340736f;
        const int colA = 32 * tt + 16 * w + n16;   // this lane's A-frag gate col
        half8v u8;
        #pragma unroll
        for (int j = 0; j < 8; j++)
            u8[j] = (__fp16)(U[(8 * g + j) * GATES + colA] * s);
        aU[tt] = u8;
        half4v w4;
        #pragma unroll
        for (int j = 0; j < 4; j++)
            w4[j] = (__fp16)(W[(4 * g + j) * GATES + colA] * s);
        aW[tt] = w4;
        float4v bv;
        #pragma unroll
        for (int r = 0; r < 4; r++)
            bv[r] = bg[32 * tt + 16 * w + 4 * g + r] * s;   // D row m = 4g+r
        bias[tt] = bv;
    }

    // zero h_0 buffer
    for (int i = tid; i < ROWS * HSTRIDE; i += 128) hbuf[0][i] = (__fp16)0.f;

    // x source: lane reads x[b0+n16][t][4g .. 4g+3] (both waves duplicate)
    const float* xrow = x + (size_t)(b0 + n16) * TSTEPS * FEAT + 4 * g;

    float4 xf0 = *reinterpret_cast<const float4*>(xrow + FEAT);        // x_1
    float4 xf1 = *reinterpret_cast<const float4*>(xrow + 2 * FEAT);    // x_2

    // accx(0) = bias + W^T·x_0^T
    float4v accx[4];
    {
        half4v a0 = pack4(*reinterpret_cast<const float4*>(xrow));
        #pragma unroll
        for (int tt = 0; tt < 4; tt++)
            accx[tt] = __builtin_amdgcn_mfma_f32_16x16x16f16(
                aW[tt], a0, bias[tt], 0, 0, 0);
    }

    float2v cst[2] = {{0.f, 0.f}, {0.f, 0.f}};
    const int hroff = n16 * HSTRIDE + 8 * g;            // B-frag read (16B)
    const int hwoff = n16 * HSTRIDE + 16 * w + 4 * g;   // h write (8B)

    __syncthreads();   // h_0 zero-init visible to both waves

    // Branch-free main loop: steps 0..195. Step t reads hbuf[t&1], writes
    // hbuf[(t+1)&1]. Invariant: xf0 = x_{t+1}, xf1 = x_{t+2}, xp = &x_t;
    // loads issued >=2 full steps before consumption AND before the next
    // barrier -- vmcnt is 0 when the barrier drains (no exposed latency).
    const float* xp = xrow;
    for (int it = 0; it < (TSTEPS - 4) / 2; ++it) {
        lstm_step<true, true, 3 * FEAT>(xf0, xp, aU, aW, bias, accx, cst,
                                        hbuf[0], hbuf[1], hroff, hwoff);
        lstm_step<true, true, 4 * FEAT>(xf1, xp, aU, aW, bias, accx, cst,
                                        hbuf[1], hbuf[0], hroff, hwoff);
        xp += 2 * FEAT;
    }
    // Peeled tail: steps 196..199 (xp == &x_196; xf0=x_197, xf1=x_198)
    lstm_step<true, true, 3 * FEAT>(xf0, xp, aU, aW, bias, accx, cst,
                                    hbuf[0], hbuf[1], hroff, hwoff);  // 196
    lstm_step<true, false, 0>(xf1, xp, aU, aW, bias, accx, cst,
                              hbuf[1], hbuf[0], hroff, hwoff);        // 197
    lstm_step<true, false, 0>(xf0, xp, aU, aW, bias, accx, cst,
                              hbuf[0], hbuf[1], hroff, hwoff);        // 198
    lstm_step<false, false, 0>(xf1, xp, aU, aW, bias, accx, cst,
                               hbuf[1], hbuf[0], hroff, hwoff);       // 199

    // h_T = h_200 lives in hbuf[0]; last step's syncthreads covers reads.
    // ---- heads: out = h_T @ W1/W2 + b (fp32, h from LDS, 128 threads) ----
    const __fp16* hf = &hbuf[0][0];
    for (int idx = tid; idx < ROWS * DOUT; idx += 128) {
        const int row = idx / DOUT;
        const int d   = idx - row * DOUT;
        float s1 = b1[d], s2 = b2[d];
        #pragma unroll 8
        for (int k = 0; k < HID; k++) {
            float hv = (float)hf[row * HSTRIDE + k];
            s1 = fmaf(hv, W1[k * DOUT + d], s1);
            s2 = fmaf(hv, W2[k * DOUT + d], s2);
        }
        out[(size_t)(b0 + row) * DOUT + d] = s1;
        out[(size_t)BATCH * DOUT + (size_t)(b0 + row) * DOUT + d] = s2;
    }
}

extern "C" void kernel_launch(void* const* d_in, const int* in_sizes, int n_in,
                              void* d_out, int out_size, void* d_ws, size_t ws_size,
                              hipStream_t stream) {
    const float* x  = (const float*)d_in[0];
    const float* W  = (const float*)d_in[1];
    const float* U  = (const float*)d_in[2];
    const float* bg = (const float*)d_in[3];
    const float* W1 = (const float*)d_in[4];
    const float* b1 = (const float*)d_in[5];
    const float* W2 = (const float*)d_in[6];
    const float* b2 = (const float*)d_in[7];
    float* out = (float*)d_out;

    dim3 grid(BATCH / ROWS);   // 512 blocks x 2 waves = 1024 waves (1/SIMD chip-wide)
    dim3 block(128);
    lstm_mfma<<<grid, block, 0, stream>>>(x, W, U, bg, W1, b1, W2, b2, out);
}

// Round 11
// 235.087 us; speedup vs baseline: 1.0847x; 1.0847x over previous
//
#include <hip/hip_runtime.h>

// Problem constants (match reference)
#define BATCH 8192
#define TSTEPS 200
#define FEAT 16
#define HID 32
#define GATES 128   // 4*HID, Keras order: i | f | cc | o
#define DOUT 60
#define ROWS 16     // batch rows per block (one MFMA N-tile)
#define HSTRIDE 40  // LDS h row stride in halves (80 B)

typedef __fp16 half2v __attribute__((ext_vector_type(2)));
typedef __fp16 half4v __attribute__((ext_vector_type(4)));
typedef __fp16 half8v __attribute__((ext_vector_type(8)));
typedef float  float2v __attribute__((ext_vector_type(2)));
typedef float  float4v __attribute__((ext_vector_type(4)));

__device__ __forceinline__ half2v pkrtz(float a, float b) {
    return __builtin_amdgcn_cvt_pkrtz(a, b);
}

__device__ __forceinline__ half4v pack4(float4 v) {
    half2v lo = pkrtz(v.x, v.y);
    half2v hi = pkrtz(v.z, v.w);
    half4v r;
    r[0] = lo[0]; r[1] = lo[1]; r[2] = hi[0]; r[3] = hi[1];
    return r;
}

// Wave-pair barrier WITHOUT the vmcnt drain (T4 / counted-vmcnt pattern).
// __syncthreads() emits s_waitcnt vmcnt(0) lgkmcnt(0) before s_barrier,
// which drains the in-flight x prefetch (streaming HBM, ~500-900 cy) every
// step -- R10's 1090 cy/step idle. Cross-wave correctness here needs only
// LDS ordering: lgkmcnt(0) drains this wave's ds_write (visibility) AND its
// ds_read of the buffer the peer overwrites next step (anti-dependence).
// x loads are lane-private VMEM: no vmcnt drain required; the compiler's
// use-site vmcnt wait sits 2 full steps after issue. sched_barrier(0) pins
// compile-time movement across the asm (rule #18 hygiene).
__device__ __forceinline__ void lds_barrier() {
    __builtin_amdgcn_sched_barrier(0);
    asm volatile("s_waitcnt lgkmcnt(0)\n\ts_barrier" ::: "memory");
    __builtin_amdgcn_sched_barrier(0);
}

// Two-wave gate-split (R10 structure, verified numerics): wave w owns
// h-units [16w, 16w+16) = gate columns 32*tt + 16*w + m, tt in {i,f,cc,o}.
// Per wave: 4 hU MFMA (16x16x32) + 4 xW MFMA (16x16x16); epilogue = 4
// outputs/lane (12 exp2 + 2 rcp, packed-f32). Lane (g,n16) holds D rows
// m=4g+r -> writes h[units 16w+4g..+3][row n16] as one 8B ds_write; next
// step's B-frag (units 8g..8g+7, row n16) is one ds_read_b128.
// 512 blocks x 2 waves = 1024 waves = 1 wave on ALL 1024 SIMDs.
// Fragment layouts (gfx950, verified R2/R4/R9):
//   16x16x32 A[m][k]: m=lane&15, k=(lane>>4)*8+j ; B[k][n]: n=lane&15, same k
//   16x16x16 A[m][k]: m=lane&15, k=(lane>>4)*4+j ; B[k][n]: n=lane&15, same k
//   D[m][n]: n=lane&15, m=(lane>>4)*4+r
// Epilogue math = R9's packed-f32 form (bit-identical numerics):
//   gates prescaled by -log2(e); num = c*d_i + relu(cc)*d_f; ee = d_i*d_f*d_o
//   c' = num*(ie*d_o); h = relu(num)*ie; ie via one rcp per element-pair.
template <bool DO_XW, bool DO_LOAD, int LOFF>
__device__ __forceinline__ void lstm_step(
    float4& XN, const float* xp,
    const half8v (&aU)[4], const half4v (&aW)[4], const float4v (&bias)[4],
    float4v (&accx)[4], float2v (&cst)[2],
    const __fp16* hr, __fp16* hw, int hroff, int hwoff)
{
    half8v hB = *reinterpret_cast<const half8v*>(&hr[hroff]);

    float4v acc[4];
    #pragma unroll
    for (int tt = 0; tt < 4; tt++)
        acc[tt] = __builtin_amdgcn_mfma_f32_16x16x32_f16(
            aU[tt], hB, accx[tt], 0, 0, 0);

    if (DO_XW) {
        half4v ax = pack4(XN);
        #pragma unroll
        for (int tt = 0; tt < 4; tt++)
            accx[tt] = __builtin_amdgcn_mfma_f32_16x16x16f16(
                aW[tt], ax, bias[tt], 0, 0, 0);
    }
    if (DO_LOAD)
        XN = *reinterpret_cast<const float4*>(xp + LOFF);

    const float2v one  = {1.0f, 1.0f};
    const float2v zero = {0.0f, 0.0f};
    union { half4v v; half2v h2[2]; } hv;
    #pragma unroll
    for (int p = 0; p < 2; p++) {
        float2v ei, ef, eo;
        ei[0] = __builtin_amdgcn_exp2f(acc[0][2 * p]);
        ei[1] = __builtin_amdgcn_exp2f(acc[0][2 * p + 1]);
        ef[0] = __builtin_amdgcn_exp2f(acc[1][2 * p]);
        ef[1] = __builtin_amdgcn_exp2f(acc[1][2 * p + 1]);
        eo[0] = __builtin_amdgcn_exp2f(acc[3][2 * p]);
        eo[1] = __builtin_amdgcn_exp2f(acc[3][2 * p + 1]);
        float2v di  = one + ei;
        float2v df  = one + ef;
        float2v dov = one + eo;
        float2v cc2 = {acc[2][2 * p], acc[2][2 * p + 1]};
        float2v rc  = __builtin_elementwise_max(cc2, zero);
        float2v num = __builtin_elementwise_fma(cst[p], di, rc * df);
        float2v ee  = (di * df) * dov;
        float   Q   = __builtin_amdgcn_rcpf(ee[0] * ee[1]);
        float2v ie  = {Q * ee[1], Q * ee[0]};
        float2v c2  = num * (ie * dov);
        cst[p] = c2;
        float2v h2  = __builtin_elementwise_max(num, zero) * ie;
        hv.h2[p] = pkrtz(h2[0], h2[1]);
    }
    *reinterpret_cast<half4v*>(&hw[hwoff]) = hv.v;   // units 16w+4g..+3, row n16
    lds_barrier();   // LDS-only sync: x loads stay in flight (no vmcnt drain)
}

__global__ __launch_bounds__(128, 1) void lstm_mfma(
    const float* __restrict__ x,    // [B, T, F]
    const float* __restrict__ W,    // [F, 128]
    const float* __restrict__ U,    // [H, 128]
    const float* __restrict__ bg,   // [128]
    const float* __restrict__ W1,   // [H, 60]
    const float* __restrict__ b1,   // [60]
    const float* __restrict__ W2,   // [H, 60]
    const float* __restrict__ b2,   // [60]
    float* __restrict__ out)        // [2 * B * 60] (long || lat)
{
    const int tid  = threadIdx.x;   // 128 threads = 2 waves
    const int lane = tid & 63;
    const int w    = tid >> 6;      // unit-half: 0 or 1
    const int n16  = lane & 15;     // batch row within tile
    const int g    = lane >> 4;     // k-quad / D-row-quad
    const int b0   = blockIdx.x * ROWS;

    __shared__ __align__(16) __fp16 hbuf[2][ROWS * HSTRIDE];

    // ---- stationary A-frags: U^T (K=32), W^T (K=16), bias (per D-row) ----
    half8v  aU[4];
    half4v  aW[4];
    float4v bias[4];
    #pragma unroll
    for (int tt = 0; tt < 4; tt++) {
        const float s = (tt == 2) ? 1.0f : -1.44269504088896340736f;
        const int colA = 32 * tt + 16 * w + n16;   // this lane's A-frag gate col
        half8v u8;
        #pragma unroll
        for (int j = 0; j < 8; j++)
            u8[j] = (__fp16)(U[(8 * g + j) * GATES + colA] * s);
        aU[tt] = u8;
        half4v w4;
        #pragma unroll
        for (int j = 0; j < 4; j++)
            w4[j] = (__fp16)(W[(4 * g + j) * GATES + colA] * s);
        aW[tt] = w4;
        float4v bv;
        #pragma unroll
        for (int r = 0; r < 4; r++)
            bv[r] = bg[32 * tt + 16 * w + 4 * g + r] * s;   // D row m = 4g+r
        bias[tt] = bv;
    }

    // zero h_0 buffer
    for (int i = tid; i < ROWS * HSTRIDE; i += 128) hbuf[0][i] = (__fp16)0.f;

    // x source: lane reads x[b0+n16][t][4g .. 4g+3] (both waves duplicate)
    const float* xrow = x + (size_t)(b0 + n16) * TSTEPS * FEAT + 4 * g;

    float4 xf0 = *reinterpret_cast<const float4*>(xrow + FEAT);        // x_1
    float4 xf1 = *reinterpret_cast<const float4*>(xrow + 2 * FEAT);    // x_2

    // accx(0) = bias + W^T·x_0^T
    float4v accx[4];
    {
        half4v a0 = pack4(*reinterpret_cast<const float4*>(xrow));
        #pragma unroll
        for (int tt = 0; tt < 4; tt++)
            accx[tt] = __builtin_amdgcn_mfma_f32_16x16x16f16(
                aW[tt], a0, bias[tt], 0, 0, 0);
    }

    float2v cst[2] = {{0.f, 0.f}, {0.f, 0.f}};
    const int hroff = n16 * HSTRIDE + 8 * g;            // B-frag read (16B)
    const int hwoff = n16 * HSTRIDE + 16 * w + 4 * g;   // h write (8B)

    __syncthreads();   // h_0 zero-init visible (once; drain cost negligible)

    // Branch-free main loop: steps 0..195. Step t reads hbuf[t&1], writes
    // hbuf[(t+1)&1]. Invariant: xf0 = x_{t+1}, xf1 = x_{t+2}, xp = &x_t.
    // Loads cross barriers un-drained; use-site vmcnt waits land 2 full
    // steps (~1400 cy) after issue.
    const float* xp = xrow;
    for (int it = 0; it < (TSTEPS - 4) / 2; ++it) {
        lstm_step<true, true, 3 * FEAT>(xf0, xp, aU, aW, bias, accx, cst,
                                        hbuf[0], hbuf[1], hroff, hwoff);
        lstm_step<true, true, 4 * FEAT>(xf1, xp, aU, aW, bias, accx, cst,
                                        hbuf[1], hbuf[0], hroff, hwoff);
        xp += 2 * FEAT;
    }
    // Peeled tail: steps 196..199 (xp == &x_196; xf0=x_197, xf1=x_198)
    lstm_step<true, true, 3 * FEAT>(xf0, xp, aU, aW, bias, accx, cst,
                                    hbuf[0], hbuf[1], hroff, hwoff);  // 196
    lstm_step<true, false, 0>(xf1, xp, aU, aW, bias, accx, cst,
                              hbuf[1], hbuf[0], hroff, hwoff);        // 197
    lstm_step<true, false, 0>(xf0, xp, aU, aW, bias, accx, cst,
                              hbuf[0], hbuf[1], hroff, hwoff);        // 198
    lstm_step<false, false, 0>(xf1, xp, aU, aW, bias, accx, cst,
                               hbuf[1], hbuf[0], hroff, hwoff);       // 199

    // h_T = h_200 lives in hbuf[0]; step 199's lds_barrier covers the reads.
    // ---- heads: out = h_T @ W1/W2 + b (fp32, h from LDS, 128 threads) ----
    const __fp16* hf = &hbuf[0][0];
    for (int idx = tid; idx < ROWS * DOUT; idx += 128) {
        const int row = idx / DOUT;
        const int d   = idx - row * DOUT;
        float s1 = b1[d], s2 = b2[d];
        #pragma unroll 8
        for (int k = 0; k < HID; k++) {
            float hv = (float)hf[row * HSTRIDE + k];
            s1 = fmaf(hv, W1[k * DOUT + d], s1);
            s2 = fmaf(hv, W2[k * DOUT + d], s2);
        }
        out[(size_t)(b0 + row) * DOUT + d] = s1;
        out[(size_t)BATCH * DOUT + (size_t)(b0 + row) * DOUT + d] = s2;
    }
}

extern "C" void kernel_launch(void* const* d_in, const int* in_sizes, int n_in,
                              void* d_out, int out_size, void* d_ws, size_t ws_size,
                              hipStream_t stream) {
    const float* x  = (const float*)d_in[0];
    const float* W  = (const float*)d_in[1];
    const float* U  = (const float*)d_in[2];
    const float* bg = (const float*)d_in[3];
    const float* W1 = (const float*)d_in[4];
    const float* b1 = (const float*)d_in[5];
    const float* W2 = (const float*)d_in[6];
    const float* b2 = (const float*)d_in[7];
    float* out = (float*)d_out;

    dim3 grid(BATCH / ROWS);   // 512 blocks x 2 waves = 1024 waves (1/SIMD chip-wide)
    dim3 block(128);
    lstm_mfma<<<grid, block, 0, stream>>>(x, W, U, bg, W1, b1, W2, b2, out);
}

// Round 12
// 209.974 us; speedup vs baseline: 1.2145x; 1.1196x over previous
//
#include <hip/hip_runtime.h>

// Problem constants (match reference)
#define BATCH 8192
#define TSTEPS 200
#define FEAT 16
#define HID 32
#define GATES 128   // 4*HID, Keras order: i | f | cc | o
#define DOUT 60
#define ROWS 16     // batch rows per block (one MFMA N-tile)
#define HSTRIDE 40  // LDS h row stride in halves (80 B)
#define NL2E -1.44269504088896340736f

typedef __fp16 half2v __attribute__((ext_vector_type(2)));
typedef __fp16 half4v __attribute__((ext_vector_type(4)));
typedef __fp16 half8v __attribute__((ext_vector_type(8)));
typedef float  float2v __attribute__((ext_vector_type(2)));
typedef float  float4v __attribute__((ext_vector_type(4)));

__device__ __forceinline__ half2v pkrtz(float a, float b) {
    return __builtin_amdgcn_cvt_pkrtz(a, b);
}

__device__ __forceinline__ half4v pack4(float4 v) {
    half2v lo = pkrtz(v.x, v.y);
    half2v hi = pkrtz(v.z, v.w);
    half4v r;
    r[0] = lo[0]; r[1] = lo[1]; r[2] = hi[0]; r[3] = hi[1];
    return r;
}

// Wave barrier WITHOUT the vmcnt drain (verified R11: -20 us vs
// __syncthreads). lgkmcnt(0) orders this wave's ds_write/ds_read around
// s_barrier; x prefetch (VMEM) stays in flight across it.
__device__ __forceinline__ void lds_barrier() {
    __builtin_amdgcn_sched_barrier(0);
    asm volatile("s_waitcnt lgkmcnt(0)\n\ts_barrier" ::: "memory");
    __builtin_amdgcn_sched_barrier(0);
}

// R12: FOUR-wave gate-split -> 2048 waves = 2 waves/SIMD chip-wide.
// Wave w (0..3) owns h-units [8w, 8w+8) = 32 gate columns, packed into TWO
// 16x16 MFMA tiles by column permutation:
//   tile 0 rows m: gate (i if (m&3)<2 else f), unit 8w + 2*(m>>2) + (m&1)
//   tile 1 rows m: gate (cc if (m&3)<2 else o), same unit mapping
// Lane (g,n16) holds D rows m=4g+r of both tiles ->
//   i2={acc0[0],acc0[1]}, f2={acc0[2],acc0[3]},
//   cc2={acc1[0],acc1[1]}, o2={acc1[2],acc1[3]}  for units 8w+2g, 8w+2g+1
// -- i/f/cc/o lane-local as natural float2 pairs. Epilogue: 6 exp2 + 1 rcp.
// h write: ONE half2 (4B) at [row n16][units 8w+2g..+1]. Next step's B-frag
// (units 8g..8g+7, row n16) = one ds_read_b128 (unchanged).
// 512 blocks x 4 waves; 2 blocks/CU -> 8 waves/CU -> 2/SIMD: the second
// wave on each SIMD fills the ~800 cy recurrence-chain latency R11 exposed.
// Fragment layouts (gfx950, verified R2/R4/R9):
//   16x16x32 A[m][k]: m=lane&15, k=(lane>>4)*8+j ; B[k][n]: n=lane&15, same k
//   16x16x16 A[m][k]: m=lane&15, k=(lane>>4)*4+j ; B[k][n]: n=lane&15, same k
//   D[m][n]: n=lane&15, m=(lane>>4)*4+r
// Epilogue math = R9/R11 packed-f32 form (bit-identical numerics):
//   gates i,f,o prescaled by -log2(e); num = c*d_i + relu(cc)*d_f;
//   ee = d_i*d_f*d_o; c' = num*(ie*d_o); h = relu(num)*ie;
//   ie = 1/ee via one rcp per element-pair.
template <bool DO_XW, bool DO_LOAD, int LOFF>
__device__ __forceinline__ void lstm_step(
    float4& XN, const float* xp,
    const half8v (&aU)[2], const half4v (&aW)[2], const float4v (&bias)[2],
    float4v (&accx)[2], float2v& cst,
    const __fp16* hr, __fp16* hw, int hroff, int hwoff)
{
    half8v hB = *reinterpret_cast<const half8v*>(&hr[hroff]);

    float4v acc0 = __builtin_amdgcn_mfma_f32_16x16x32_f16(
        aU[0], hB, accx[0], 0, 0, 0);
    float4v acc1 = __builtin_amdgcn_mfma_f32_16x16x32_f16(
        aU[1], hB, accx[1], 0, 0, 0);

    if (DO_XW) {
        half4v ax = pack4(XN);
        accx[0] = __builtin_amdgcn_mfma_f32_16x16x16f16(
            aW[0], ax, bias[0], 0, 0, 0);
        accx[1] = __builtin_amdgcn_mfma_f32_16x16x16f16(
            aW[1], ax, bias[1], 0, 0, 0);
    }
    if (DO_LOAD)
        XN = *reinterpret_cast<const float4*>(xp + LOFF);

    const float2v one  = {1.0f, 1.0f};
    const float2v zero = {0.0f, 0.0f};
    float2v ei, ef, eo;
    ei[0] = __builtin_amdgcn_exp2f(acc0[0]);
    ei[1] = __builtin_amdgcn_exp2f(acc0[1]);
    ef[0] = __builtin_amdgcn_exp2f(acc0[2]);
    ef[1] = __builtin_amdgcn_exp2f(acc0[3]);
    eo[0] = __builtin_amdgcn_exp2f(acc1[2]);
    eo[1] = __builtin_amdgcn_exp2f(acc1[3]);
    float2v di  = one + ei;
    float2v df  = one + ef;
    float2v dov = one + eo;
    float2v cc2 = {acc1[0], acc1[1]};
    float2v rc  = __builtin_elementwise_max(cc2, zero);
    float2v num = __builtin_elementwise_fma(cst, di, rc * df);
    float2v ee  = (di * df) * dov;
    float   Q   = __builtin_amdgcn_rcpf(ee[0] * ee[1]);
    float2v ie  = {Q * ee[1], Q * ee[0]};
    float2v c2  = num * (ie * dov);
    cst = c2;
    float2v h2  = __builtin_elementwise_max(num, zero) * ie;
    *reinterpret_cast<half2v*>(&hw[hwoff]) = pkrtz(h2[0], h2[1]);

    lds_barrier();   // LDS-only sync: x loads stay in flight (no vmcnt drain)
}

__global__ __launch_bounds__(256, 1) void lstm_mfma(
    const float* __restrict__ x,    // [B, T, F]
    const float* __restrict__ W,    // [F, 128]
    const float* __restrict__ U,    // [H, 128]
    const float* __restrict__ bg,   // [128]
    const float* __restrict__ W1,   // [H, 60]
    const float* __restrict__ b1,   // [60]
    const float* __restrict__ W2,   // [H, 60]
    const float* __restrict__ b2,   // [60]
    float* __restrict__ out)        // [2 * B * 60] (long || lat)
{
    const int tid  = threadIdx.x;   // 256 threads = 4 waves
    const int lane = tid & 63;
    const int w    = tid >> 6;      // unit-octet: 0..3
    const int n16  = lane & 15;     // batch row within tile
    const int g    = lane >> 4;     // k-quad / D-row-quad
    const int b0   = blockIdx.x * ROWS;

    __shared__ __align__(16) __fp16 hbuf[2][ROWS * HSTRIDE];

    // ---- stationary A-frags: U^T (K=32), W^T (K=16), bias (per D-row) ----
    // Column map (tile tt2, D row m): gate = 2*tt2 + ((m&3)>>1);
    // col = 32*gate + 8*w + 2*(m>>2) + (m&1); scale 1.0 for cc, -log2e else.
    half8v  aU[2];
    half4v  aW[2];
    float4v bias[2];
    #pragma unroll
    for (int tt2 = 0; tt2 < 2; tt2++) {
        const int gA   = 2 * tt2 + ((n16 >> 1) & 1);       // gate of A column
        const float sA = (gA == 2) ? 1.0f : NL2E;
        const int colA = 32 * gA + 8 * w + 2 * (n16 >> 2) + (n16 & 1);
        half8v u8;
        #pragma unroll
        for (int j = 0; j < 8; j++)
            u8[j] = (__fp16)(U[(8 * g + j) * GATES + colA] * sA);
        aU[tt2] = u8;
        half4v w4;
        #pragma unroll
        for (int j = 0; j < 4; j++)
            w4[j] = (__fp16)(W[(4 * g + j) * GATES + colA] * sA);
        aW[tt2] = w4;
        float4v bv;
        #pragma unroll
        for (int r = 0; r < 4; r++) {
            const int gi = 2 * tt2 + (r >> 1);
            const int cb = 32 * gi + 8 * w + 2 * g + (r & 1);
            bv[r] = bg[cb] * ((gi == 2) ? 1.0f : NL2E);
        }
        bias[tt2] = bv;
    }

    // zero h_0 buffer
    for (int i = tid; i < ROWS * HSTRIDE; i += 256) hbuf[0][i] = (__fp16)0.f;

    // x source: lane reads x[b0+n16][t][4g .. 4g+3] (all 4 waves duplicate;
    // same-block duplicates hit L1/L2)
    const float* xrow = x + (size_t)(b0 + n16) * TSTEPS * FEAT + 4 * g;

    float4 xf0 = *reinterpret_cast<const float4*>(xrow + FEAT);        // x_1
    float4 xf1 = *reinterpret_cast<const float4*>(xrow + 2 * FEAT);    // x_2

    // accx(0) = bias + W^T·x_0^T
    float4v accx[2];
    {
        half4v a0 = pack4(*reinterpret_cast<const float4*>(xrow));
        accx[0] = __builtin_amdgcn_mfma_f32_16x16x16f16(
            aW[0], a0, bias[0], 0, 0, 0);
        accx[1] = __builtin_amdgcn_mfma_f32_16x16x16f16(
            aW[1], a0, bias[1], 0, 0, 0);
    }

    float2v cst = {0.f, 0.f};
    const int hroff = n16 * HSTRIDE + 8 * g;           // B-frag read (16B)
    const int hwoff = n16 * HSTRIDE + 8 * w + 2 * g;   // h write (4B, half2)

    __syncthreads();   // h_0 zero-init visible (once; drain cost negligible)

    // Branch-free main loop: steps 0..195. Step t reads hbuf[t&1], writes
    // hbuf[(t+1)&1]. Invariant: xf0 = x_{t+1}, xf1 = x_{t+2}, xp = &x_t.
    // Loads cross barriers un-drained; use-site vmcnt waits land 2 full
    // steps after issue.
    const float* xp = xrow;
    for (int it = 0; it < (TSTEPS - 4) / 2; ++it) {
        lstm_step<true, true, 3 * FEAT>(xf0, xp, aU, aW, bias, accx, cst,
                                        hbuf[0], hbuf[1], hroff, hwoff);
        lstm_step<true, true, 4 * FEAT>(xf1, xp, aU, aW, bias, accx, cst,
                                        hbuf[1], hbuf[0], hroff, hwoff);
        xp += 2 * FEAT;
    }
    // Peeled tail: steps 196..199 (xp == &x_196; xf0=x_197, xf1=x_198)
    lstm_step<true, true, 3 * FEAT>(xf0, xp, aU, aW, bias, accx, cst,
                                    hbuf[0], hbuf[1], hroff, hwoff);  // 196
    lstm_step<true, false, 0>(xf1, xp, aU, aW, bias, accx, cst,
                              hbuf[1], hbuf[0], hroff, hwoff);        // 197
    lstm_step<true, false, 0>(xf0, xp, aU, aW, bias, accx, cst,
                              hbuf[0], hbuf[1], hroff, hwoff);        // 198
    lstm_step<false, false, 0>(xf1, xp, aU, aW, bias, accx, cst,
                               hbuf[1], hbuf[0], hroff, hwoff);       // 199

    // h_T = h_200 lives in hbuf[0]; step 199's lds_barrier covers the reads.
    // ---- heads: out = h_T @ W1/W2 + b (fp32, h from LDS, 256 threads) ----
    const __fp16* hf = &hbuf[0][0];
    for (int idx = tid; idx < ROWS * DOUT; idx += 256) {
        const int row = idx / DOUT;
        const int d   = idx - row * DOUT;
        float s1 = b1[d], s2 = b2[d];
        #pragma unroll 8
        for (int k = 0; k < HID; k++) {
            float hv = (float)hf[row * HSTRIDE + k];
            s1 = fmaf(hv, W1[k * DOUT + d], s1);
            s2 = fmaf(hv, W2[k * DOUT + d], s2);
        }
        out[(size_t)(b0 + row) * DOUT + d] = s1;
        out[(size_t)BATCH * DOUT + (size_t)(b0 + row) * DOUT + d] = s2;
    }
}

extern "C" void kernel_launch(void* const* d_in, const int* in_sizes, int n_in,
                              void* d_out, int out_size, void* d_ws, size_t ws_size,
                              hipStream_t stream) {
    const float* x  = (const float*)d_in[0];
    const float* W  = (const float*)d_in[1];
    const float* U  = (const float*)d_in[2];
    const float* bg = (const float*)d_in[3];
    const float* W1 = (const float*)d_in[4];
    const float* b1 = (const float*)d_in[5];
    const float* W2 = (const float*)d_in[6];
    const float* b2 = (const float*)d_in[7];
    float* out = (float*)d_out;

    dim3 grid(BATCH / ROWS);   // 512 blocks x 4 waves = 2048 waves (2/SIMD)
    dim3 block(256);
    lstm_mfma<<<grid, block, 0, stream>>>(x, W, U, bg, W1, b1, W2, b2, out);
}